// Round 8
// baseline (581.172 us; speedup 1.0000x reference)
//
#include <hip/hip_runtime.h>
#include <hip/hip_bf16.h>

#define NEG_SLOPE 0.2f

using bf16 = __hip_bfloat16;

__device__ __forceinline__ float tof(bf16 v) { return __bfloat162float(v); }
__device__ __forceinline__ float tof(float v) { return v; }
__device__ __forceinline__ void store_val(bf16* p, float v) { *p = __float2bfloat16(v); }
__device__ __forceinline__ void store_val(float* p, float v) { *p = v; }

// load 8 consecutive elems of T as fp32 (16B for bf16, 32B for fp32)
template <typename T>
__device__ __forceinline__ void load8(const T* p, float* o) {
    if constexpr (sizeof(T) == 2) {
        uint4 raw = *(const uint4*)p;
        const bf16* h = (const bf16*)&raw;
#pragma unroll
        for (int k = 0; k < 8; ++k) o[k] = tof(h[k]);
    } else {
        float4 r0 = *(const float4*)p;
        float4 r1 = *(const float4*)(p + 4);
        o[0] = r0.x; o[1] = r0.y; o[2] = r0.z; o[3] = r0.w;
        o[4] = r1.x; o[5] = r1.y; o[6] = r1.z; o[7] = r1.w;
    }
}

// load 4 consecutive elems of T as fp32 (8B for bf16, 16B for fp32)
template <typename T>
__device__ __forceinline__ void load4(const T* p, float* o) {
    if constexpr (sizeof(T) == 2) {
        uint2 raw = *(const uint2*)p;
        const bf16* h = (const bf16*)&raw;
#pragma unroll
        for (int k = 0; k < 4; ++k) o[k] = tof(h[k]);
    } else {
        float4 r = *(const float4*)p;
        o[0] = r.x; o[1] = r.y; o[2] = r.z; o[3] = r.w;
    }
}

// Parallel dtype detect via ballot (validated r6/r7).
__device__ __forceinline__ int detect_ballot(const void* x0, int tid, int* flag4) {
    bool bad = false;
    if (tid < 128) {
        unsigned short u = ((const unsigned short*)x0)[tid];
        float v = __uint_as_float(((unsigned int)u) << 16);
        bad = !(fabsf(v) < 100.f);   // catches NaN too
    }
    unsigned long long m = __ballot(bad);
    if ((tid & 63) == 0) flag4[tid >> 6] = (m != 0ULL);
    __syncthreads();
    return flag4[0] | flag4[1] | flag4[2] | flag4[3];
}

// Stage NS rows of F elems into LDS (row stride FP, fp32). (fallback path)
template <typename T, int F, int NS, int FP>
__device__ __forceinline__ void stage(float* xs, const T* self, const T* neigh, int tid) {
    constexpr int V = 16 / sizeof(T);
    constexpr int TOT = NS * F / V;
    for (int i = tid; i < TOT; i += 256) {
        int e = i * V;
        int s = e / F, f = e % F;
        const T* src = (s == 0) ? (self + f) : (neigh + (size_t)(s - 1) * F + f);
        uint4 raw = *(const uint4*)src;
        const T* hv = (const T*)&raw;
        float* dst = &xs[s * FP + f];
#pragma unroll
        for (int k = 0; k < V; ++k) dst[k] = tof(hv[k]);
    }
}

// ---- wave-parallel logits + leaky_relu + softmax (validated; root3/fallback)
template <typename T, int F, int NS, int FP>
__device__ __forceinline__ void attention2(const float* xs, const T* a_self,
                                           const T* a_neigh, float (*attnT)[4],
                                           float* part, int tid) {
    const int half = tid >> 7;
    const int grp  = (tid >> 5) & 3;
    const int u    = tid & 31;
    float val = 0.f;
    if (u <= NS) {
        const T* a = ((u < NS) ? a_neigh : a_self) + (size_t)grp * F;
        const float* xrow = xs + (size_t)(u < NS ? u : 0) * FP;
        const int f0 = half * (F / 2);
        float s0 = 0.f, s1 = 0.f, s2 = 0.f, s3 = 0.f;
        float s4 = 0.f, s5 = 0.f, s6 = 0.f, s7 = 0.f;
#pragma unroll 2
        for (int f = f0; f < f0 + F / 2; f += 8) {
            float av[8];
            load8(a + f, av);
            float4 x0 = *(const float4*)(xrow + f);
            float4 x1 = *(const float4*)(xrow + f + 4);
            s0 += x0.x * av[0]; s1 += x0.y * av[1];
            s2 += x0.z * av[2]; s3 += x0.w * av[3];
            s4 += x1.x * av[4]; s5 += x1.y * av[5];
            s6 += x1.z * av[6]; s7 += x1.w * av[7];
        }
        val = ((s0 + s1) + (s2 + s3)) + ((s4 + s5) + (s6 + s7));
    }
    part[tid] = val;
    __syncthreads();
    if (half == 0) {
        float v = part[tid] + part[tid + 128];
        float ls = __shfl(v, NS, 32);
        float x = -1e30f;
        if (u < NS) {
            float t = ls + v;
            x = (t > 0.f) ? t : NEG_SLOPE * t;
        }
        float m = x;
#pragma unroll
        for (int off = 16; off; off >>= 1) m = fmaxf(m, __shfl_xor(m, off, 32));
        float e = (u < NS) ? __expf(x - m) : 0.f;
        float s = e;
#pragma unroll
        for (int off = 16; off; off >>= 1) s += __shfl_xor(s, off, 32);
        if (u < NS) attnT[u][grp] = e / s;
    }
    __syncthreads();
}

// ===================== Kernel 1: level-0, fused stage+logit (v5) ============
// Thread (u = tid>>3, c = tid&7): u = sample row (0 = self; 31 = self-logit),
// c = f-slice. Thread owns floats {c*4 + j*32 + k, j=0..7, k=0..3}:
//  - global load4 once; LDS write at u*1040 + c*16 + j*128 bytes -> each
//    quarter-wave covers all 32 banks <=2x (free; r5's c*32 layout was 8-way);
//  - all-4-head logit partials FMA'd from the register copy (a from L1);
//  - partials at part2[u*36 + c*4 + h] (u-stride = 4 banks: 2-way write).
// Then shuffle softmax (validated) and r3's conflict-free aggregate.
template <typename T, int NS>
__device__ __forceinline__ void agg0v5_core(
    const T* self, const T* neigh, const T* a_s, const T* a_n,
    float* dst, float* xs, float* part2, float* attnT, int tid)
{
    const int u = tid >> 3, c = tid & 7;
    if (u < NS || u == 31) {
        const bool sl = (u == 31);
        const T* src = (sl || u == 0) ? self : (neigh + (size_t)(u - 1) * 256);
        const T* a = sl ? a_s : a_n;
        float* ld = &xs[u * 260];
        float acc0 = 0.f, acc1 = 0.f, acc2 = 0.f, acc3 = 0.f;
#pragma unroll
        for (int j = 0; j < 8; ++j) {
            const int f = c * 4 + j * 32;
            float xv[4], av[4];
            load4(src + f, xv);
            if (!sl) *(float4*)&ld[f] = make_float4(xv[0], xv[1], xv[2], xv[3]);
            load4(a + 0 * 256 + f, av);
            acc0 += xv[0]*av[0] + xv[1]*av[1] + xv[2]*av[2] + xv[3]*av[3];
            load4(a + 1 * 256 + f, av);
            acc1 += xv[0]*av[0] + xv[1]*av[1] + xv[2]*av[2] + xv[3]*av[3];
            load4(a + 2 * 256 + f, av);
            acc2 += xv[0]*av[0] + xv[1]*av[1] + xv[2]*av[2] + xv[3]*av[3];
            load4(a + 3 * 256 + f, av);
            acc3 += xv[0]*av[0] + xv[1]*av[1] + xv[2]*av[2] + xv[3]*av[3];
        }
        *(float4*)&part2[u * 36 + c * 4] = make_float4(acc0, acc1, acc2, acc3);
    }
    __syncthreads();
    // softmax: 128 threads = 32 samples x 4 heads, shuffle over 32-lane groups
    if (tid < 128) {
        const int su = tid & 31, h = tid >> 5;
        float v = 0.f;
        if (su < NS || su == 31) {
#pragma unroll
            for (int cc = 0; cc < 8; ++cc) v += part2[su * 36 + cc * 4 + h];
        }
        float ls = __shfl(v, 31, 32);   // self logit lives in lane 31
        float x = -1e30f;
        if (su < NS) { float t = ls + v; x = (t > 0.f) ? t : NEG_SLOPE * t; }
        float m = x;
#pragma unroll
        for (int off = 16; off; off >>= 1) m = fmaxf(m, __shfl_xor(m, off, 32));
        float e = (su < NS) ? __expf(x - m) : 0.f;
        float s = e;
#pragma unroll
        for (int off = 16; off; off >>= 1) s += __shfl_xor(s, off, 32);
        if (su < NS) attnT[su * 4 + h] = e / s;
    }
    __syncthreads();
    // aggregate: thread = feature column (r3-proven pattern)
    {
        float a0 = 0.f, a1 = 0.f, a2 = 0.f, a3 = 0.f;
#pragma unroll
        for (int s = 0; s < NS; ++s) {
            float4 w = *(const float4*)&attnT[s * 4];   // uniform -> broadcast
            float xv = xs[s * 260 + tid];
            a0 += w.x * xv; a1 += w.y * xv; a2 += w.z * xv; a3 += w.w * xv;
        }
        dst[tid] = a0; dst[256 + tid] = a1; dst[512 + tid] = a2; dst[768 + tid] = a3;
    }
}

__global__ __launch_bounds__(256) void gat_agg0v5(
    const void* x0, const void* x1, const void* x2,
    const void* a0s, const void* a0n, float* xbar0)
{
    const int node = blockIdx.x % 11;
    const int b = blockIdx.x / 11;
    const int tid = threadIdx.x;
    __shared__ __align__(16) float xs[26 * 260];     // 27040 B
    __shared__ __align__(16) float part2[32 * 36];   // 4608 B
    __shared__ __align__(16) float attnT[128];       // 512 B  (total ~32.2 KB -> 5 blk/CU)
    __shared__ int flag4[4];
    float* dst = xbar0 + (size_t)blockIdx.x * 1024;
    if (detect_ballot(x0, tid, flag4)) {
        const float *X0 = (const float*)x0, *X1 = (const float*)x1, *X2 = (const float*)x2;
        const float *As = (const float*)a0s, *An = (const float*)a0n;
        if (node == 0)
            agg0v5_core<float, 11>(X0 + (size_t)b * 256, X1 + (size_t)b * 2560,
                                   As, An, dst, xs, part2, attnT, tid);
        else {
            int p = node - 1;
            agg0v5_core<float, 26>(X1 + ((size_t)b * 10 + p) * 256,
                                   X2 + ((size_t)b * 250 + (size_t)p * 25) * 256,
                                   As, An, dst, xs, part2, attnT, tid);
        }
    } else {
        const bf16 *X0 = (const bf16*)x0, *X1 = (const bf16*)x1, *X2 = (const bf16*)x2;
        const bf16 *As = (const bf16*)a0s, *An = (const bf16*)a0n;
        if (node == 0)
            agg0v5_core<bf16, 11>(X0 + (size_t)b * 256, X1 + (size_t)b * 2560,
                                  As, An, dst, xs, part2, attnT, tid);
        else {
            int p = node - 1;
            agg0v5_core<bf16, 26>(X1 + ((size_t)b * 10 + p) * 256,
                                  X2 + ((size_t)b * 250 + (size_t)p * 25) * 256,
                                  As, An, dst, xs, part2, attnT, tid);
        }
    }
}

// ===================== Kernel 2: level-0 transform GEMM (r4-proven 128-tile) =
// Y[n][h*128+d] = sum_k X[n][h*256+k] * W[h][k][d]. Tile 128m x 128d, 8x8
// register tile. X staged transposed in LDS ([k][m], pad 132, b128 frags);
// W streamed from L1 (16 KB chunk resident, broadcast across ty).
template <typename T>
__device__ __forceinline__ void gemm0_body(const float* __restrict__ X,
                                           const T* __restrict__ W,
                                           float* __restrict__ Y,
                                           float* xt, int mtiles, int bid, int tid)
{
    const int h = bid / mtiles, mt = bid % mtiles;
    const int n0 = mt * 128;
    const int tx = tid & 15, ty = tid >> 4;
    const T* Wh = W + (size_t)h * 256 * 128 + tx * 8;
    float acc[8][8];
#pragma unroll
    for (int m = 0; m < 8; ++m)
#pragma unroll
        for (int d = 0; d < 8; ++d) acc[m][d] = 0.f;

    for (int kc = 0; kc < 256; kc += 32) {
        __syncthreads();
#pragma unroll
        for (int t = 0; t < 4; ++t) {
            int i = tid + t * 256;
            int r = i >> 3, c = (i & 7) << 2;
            float4 v = *(const float4*)(X + (size_t)(n0 + r) * 1024 + h * 256 + kc + c);
            xt[(c + 0) * 132 + r] = v.x;
            xt[(c + 1) * 132 + r] = v.y;
            xt[(c + 2) * 132 + r] = v.z;
            xt[(c + 3) * 132 + r] = v.w;
        }
        __syncthreads();
#pragma unroll 2
        for (int k = 0; k < 32; ++k) {
            float wv[8];
            load8(Wh + (size_t)(kc + k) * 128, wv);
            float xv[8];
            *(float4*)&xv[0] = *(const float4*)&xt[k * 132 + ty * 8];
            *(float4*)&xv[4] = *(const float4*)&xt[k * 132 + ty * 8 + 4];
#pragma unroll
            for (int m = 0; m < 8; ++m)
#pragma unroll
                for (int d = 0; d < 8; ++d) acc[m][d] += xv[m] * wv[d];
        }
    }
#pragma unroll
    for (int m = 0; m < 8; ++m) {
        float* yp = Y + (size_t)(n0 + ty * 8 + m) * 512 + h * 128 + tx * 8;
        *(float4*)(yp + 0) = make_float4(acc[m][0], acc[m][1], acc[m][2], acc[m][3]);
        *(float4*)(yp + 4) = make_float4(acc[m][4], acc[m][5], acc[m][6], acc[m][7]);
    }
}

__global__ __launch_bounds__(256) void gat_gemm0(
    const void* x0, const float* X, const void* W, float* Y)
{
    __shared__ __align__(16) float xt[32 * 132];
    __shared__ int flag4[4];
    const int tid = threadIdx.x;
    const int mtiles = gridDim.x >> 2;
    if (detect_ballot(x0, tid, flag4))
        gemm0_body<float>(X, (const float*)W, Y, xt, mtiles, blockIdx.x, tid);
    else
        gemm0_body<bf16>(X, (const bf16*)W, Y, xt, mtiles, blockIdx.x, tid);
}

// ===================== Kernel 3: root layer, G=4 per block (r7-proven) ======
template <typename T>
__device__ __forceinline__ void root3_body(
    const float* hsws, const T* w1, const T* a1s, const T* a1n, const T* fcw,
    T* out, float* hs, float* xbarAll, float (*attnT)[4], float* part,
    int b0, int tid)
{
    for (int g = 0; g < 4; ++g) {
        int b = b0 + g;
        for (int i = tid; i < 11 * 128; i += 256) {
            int s = i >> 7, f = (i & 127) << 2;
            *(float4*)&hs[s * 516 + f] =
                *(const float4*)(hsws + ((size_t)b * 11 + s) * 512 + f);
        }
        __syncthreads();
        attention2<T, 512, 11, 516>(hs, a1s, a1n, attnT, part, tid);
        float* xbar = xbarAll + g * 2080;
        {
            float a00=0,a01=0,a10=0,a11=0,a20=0,a21=0,a30=0,a31=0;
#pragma unroll
            for (int s = 0; s < 11; ++s) {
                float4 w = *(const float4*)attnT[s];
                float xv0 = hs[s * 516 + tid], xv1 = hs[s * 516 + tid + 256];
                a00 += w.x * xv0; a01 += w.x * xv1;
                a10 += w.y * xv0; a11 += w.y * xv1;
                a20 += w.z * xv0; a21 += w.z * xv1;
                a30 += w.w * xv0; a31 += w.w * xv1;
            }
            int k0 = tid, k1 = tid + 256;
            int o0 = k0 + (k0 >> 7), o1 = k1 + (k1 >> 7);
            xbar[0 * 520 + o0] = a00; xbar[0 * 520 + o1] = a01;
            xbar[1 * 520 + o0] = a10; xbar[1 * 520 + o1] = a11;
            xbar[2 * 520 + o0] = a20; xbar[2 * 520 + o1] = a21;
            xbar[3 * 520 + o0] = a30; xbar[3 * 520 + o1] = a31;
        }
        __syncthreads();
    }

    {
        const int q = tid & 3, g2 = tid >> 2;
        const int h = g2 >> 4, d0 = (g2 & 15) * 8;
        const T* wp = w1 + (size_t)h * 512 * 128 + d0;
        float acc[4][8];
#pragma unroll
        for (int g = 0; g < 4; ++g)
#pragma unroll
            for (int j = 0; j < 8; ++j) acc[g][j] = 0.f;
#pragma unroll 2
        for (int i = 0; i < 128; ++i) {
            float wv[8];
            load8(wp + (size_t)(q * 128 + i) * 128, wv);
#pragma unroll
            for (int g = 0; g < 4; ++g) {
                float xv = xbarAll[g * 2080 + h * 520 + q * 129 + i];
#pragma unroll
                for (int j = 0; j < 8; ++j) acc[g][j] += xv * wv[j];
            }
        }
        __syncthreads();
        float* red = xbarAll;
#pragma unroll
        for (int g = 0; g < 4; ++g) {
            float* r = &red[(q * 64 + g2) * 33 + g * 8];
            *(float4*)(r + 0) = make_float4(acc[g][0], acc[g][1], acc[g][2], acc[g][3]);
            *(float4*)(r + 4) = make_float4(acc[g][4], acc[g][5], acc[g][6], acc[g][7]);
        }
    }
    __syncthreads();
    {
        const int g = tid & 3, t = tid >> 2;
        float s8[8] = {0,0,0,0,0,0,0,0};
#pragma unroll
        for (int q2 = 0; q2 < 4; ++q2) {
            const float* rr = &xbarAll[(q2 * 64 + t) * 33 + g * 8];
            float4 p0 = *(const float4*)rr, p1 = *(const float4*)(rr + 4);
            s8[0] += p0.x; s8[1] += p0.y; s8[2] += p0.z; s8[3] += p0.w;
            s8[4] += p1.x; s8[5] += p1.y; s8[6] += p1.z; s8[7] += p1.w;
        }
        int f0 = (t >> 4) * 128 + (t & 15) * 8;
        float* hp = &hs[g * 545 + f0 + 4 * (f0 >> 6)];
        *(float4*)(hp + 0) = make_float4(s8[0], s8[1], s8[2], s8[3]);
        *(float4*)(hp + 4) = make_float4(s8[4], s8[5], s8[6], s8[7]);
    }
    __syncthreads();
    {
        const int fq = tid >> 5, jb = tid & 31;
        float acc[4][8];
#pragma unroll
        for (int g = 0; g < 4; ++g)
#pragma unroll
            for (int j = 0; j < 8; ++j) acc[g][j] = 0.f;
#pragma unroll 2
        for (int i = 0; i < 64; ++i) {
            float wv[8];
            load8(fcw + (size_t)(fq * 64 + i) * 256 + jb * 8, wv);
#pragma unroll
            for (int g = 0; g < 4; ++g) {
                float xv = hs[g * 545 + fq * 68 + i];
#pragma unroll
                for (int j = 0; j < 8; ++j) acc[g][j] += xv * wv[j];
            }
        }
        __syncthreads();
        float* red2 = xbarAll;
#pragma unroll
        for (int g = 0; g < 4; ++g) {
            float* r = &red2[(fq * 32 + jb) * 33 + g * 8];
            *(float4*)(r + 0) = make_float4(acc[g][0], acc[g][1], acc[g][2], acc[g][3]);
            *(float4*)(r + 4) = make_float4(acc[g][4], acc[g][5], acc[g][6], acc[g][7]);
        }
    }
    __syncthreads();
    if (tid < 128) {
        const int g = tid >> 5, jb = tid & 31;
        float s8[8] = {0,0,0,0,0,0,0,0};
#pragma unroll
        for (int q2 = 0; q2 < 8; ++q2) {
            const float* rr = &xbarAll[(q2 * 32 + jb) * 33 + g * 8];
            float4 p0 = *(const float4*)rr, p1 = *(const float4*)(rr + 4);
            s8[0] += p0.x; s8[1] += p0.y; s8[2] += p0.z; s8[3] += p0.w;
            s8[4] += p1.x; s8[5] += p1.y; s8[6] += p1.z; s8[7] += p1.w;
        }
        T* op = out + (size_t)(b0 + g) * 256 + jb * 8;
#pragma unroll
        for (int j = 0; j < 8; ++j) store_val(op + j, s8[j]);
    }
}

__global__ __launch_bounds__(256) void gat_root3(
    const void* x0, const float* hsws, const void* w1, const void* a1s,
    const void* a1n, const void* fcw, void* out)
{
    const int b0 = blockIdx.x * 4;
    const int tid = threadIdx.x;
    __shared__ __align__(16) float hs[11 * 516];
    __shared__ __align__(16) float xbarAll[8448];
    __shared__ __align__(16) float attnT[26][4];
    __shared__ float part[256];
    __shared__ int flag4[4];
    if (detect_ballot(x0, tid, flag4))
        root3_body<float>(hsws, (const float*)w1, (const float*)a1s,
                          (const float*)a1n, (const float*)fcw, (float*)out,
                          hs, xbarAll, attnT, part, b0, tid);
    else
        root3_body<bf16>(hsws, (const bf16*)w1, (const bf16*)a1s,
                         (const bf16*)a1n, (const bf16*)fcw, (bf16*)out,
                         hs, xbarAll, attnT, part, b0, tid);
}

// ================= Fallback: fully-fused single kernel (ws-less) ============
template <int F, int NS, int FP>
__device__ __forceinline__ void aggregate2(const float* xs, const float (*attnT)[4],
                                           float* xbar, int tid) {
    constexpr int FCH = F / 256;
    float acc[4][FCH];
#pragma unroll
    for (int h = 0; h < 4; ++h)
#pragma unroll
        for (int c = 0; c < FCH; ++c) acc[h][c] = 0.f;
#pragma unroll
    for (int s = 0; s < NS; ++s) {
        float4 w = *(const float4*)attnT[s];
#pragma unroll
        for (int c = 0; c < FCH; ++c) {
            float xv = xs[(size_t)s * FP + tid + c * 256];
            acc[0][c] += w.x * xv;
            acc[1][c] += w.y * xv;
            acc[2][c] += w.z * xv;
            acc[3][c] += w.w * xv;
        }
    }
#pragma unroll
    for (int c = 0; c < FCH; ++c)
#pragma unroll
        for (int h = 0; h < 4; ++h)
            xbar[h * F + tid + c * 256] = acc[h][c];
}

template <typename T, int F>
__device__ __forceinline__ void transform_o(const float* xbar, const T* w,
                                            float* dst, int tid) {
#pragma unroll
    for (int r = 0; r < 2; ++r) {
        int o = tid + r * 256;
        int h = o >> 7, d = o & 127;
        const T* wp = w + (size_t)h * F * 128 + d;
        const float* xb = xbar + (size_t)h * F;
        float a0 = 0.f, a1 = 0.f, a2 = 0.f, a3 = 0.f;
        for (int f = 0; f < F; f += 4) {
            a0 += xb[f + 0] * tof(wp[(size_t)(f + 0) * 128]);
            a1 += xb[f + 1] * tof(wp[(size_t)(f + 1) * 128]);
            a2 += xb[f + 2] * tof(wp[(size_t)(f + 2) * 128]);
            a3 += xb[f + 3] * tof(wp[(size_t)(f + 3) * 128]);
        }
        dst[o] = (a0 + a1) + (a2 + a3);
    }
}

template <typename T>
__device__ __forceinline__ void gat_body_fb(
    const T* x0, const T* x1, const T* x2, const T* w0, const T* a0s,
    const T* a0n, const T* w1, const T* a1s, const T* a1n, const T* fcw,
    T* out, float* xs, float* hs, float* xbar, float (*attnT)[4],
    float* part, float* hroot, int b, int tid)
{
    for (int p = 0; p < 10; ++p) {
        stage<T, 256, 26, 260>(xs, x1 + ((size_t)b * 10 + p) * 256,
                               x2 + ((size_t)b * 250 + (size_t)p * 25) * 256, tid);
        __syncthreads();
        attention2<T, 256, 26, 260>(xs, a0s, a0n, attnT, part, tid);
        aggregate2<256, 26, 260>(xs, attnT, xbar, tid);
        __syncthreads();
        transform_o<T, 256>(xbar, w0, &hs[(p + 1) * 516], tid);
        __syncthreads();
    }
    stage<T, 256, 11, 260>(xs, x0 + (size_t)b * 256, x1 + (size_t)b * 2560, tid);
    __syncthreads();
    attention2<T, 256, 11, 260>(xs, a0s, a0n, attnT, part, tid);
    aggregate2<256, 11, 260>(xs, attnT, xbar, tid);
    __syncthreads();
    transform_o<T, 256>(xbar, w0, &hs[0], tid);
    __syncthreads();
    attention2<T, 512, 11, 516>(hs, a1s, a1n, attnT, part, tid);
    aggregate2<512, 11, 516>(hs, attnT, xbar, tid);
    __syncthreads();
    transform_o<T, 512>(xbar, w1, hroot, tid);
    __syncthreads();
    const T* fp = fcw + tid;
    float a0 = 0.f, a1 = 0.f, a2 = 0.f, a3 = 0.f;
    for (int f = 0; f < 512; f += 4) {
        a0 += hroot[f + 0] * tof(fp[(size_t)(f + 0) * 256]);
        a1 += hroot[f + 1] * tof(fp[(size_t)(f + 1) * 256]);
        a2 += hroot[f + 2] * tof(fp[(size_t)(f + 2) * 256]);
        a3 += hroot[f + 3] * tof(fp[(size_t)(f + 3) * 256]);
    }
    store_val(&out[(size_t)b * 256 + tid], (a0 + a1) + (a2 + a3));
}

__global__ __launch_bounds__(256) void gat_fused(
    const void* x0, const void* x1, const void* x2, const void* w0,
    const void* a0s, const void* a0n, const void* w1, const void* a1s,
    const void* a1n, const void* fcw, void* out)
{
    const int b = blockIdx.x;
    const int tid = threadIdx.x;
    __shared__ __align__(16) float xs[26 * 260];
    __shared__ __align__(16) float hs[11 * 516];
    __shared__ __align__(16) float xbar[4 * 512];
    __shared__ __align__(16) float attnT[26][4];
    __shared__ float part[256];
    __shared__ __align__(16) float hroot[512];
    __shared__ int flag4[4];
    if (detect_ballot(x0, tid, flag4))
        gat_body_fb<float>((const float*)x0, (const float*)x1, (const float*)x2,
                           (const float*)w0, (const float*)a0s, (const float*)a0n,
                           (const float*)w1, (const float*)a1s, (const float*)a1n,
                           (const float*)fcw, (float*)out,
                           xs, hs, xbar, attnT, part, hroot, b, tid);
    else
        gat_body_fb<bf16>((const bf16*)x0, (const bf16*)x1, (const bf16*)x2,
                          (const bf16*)w0, (const bf16*)a0s, (const bf16*)a0n,
                          (const bf16*)w1, (const bf16*)a1s, (const bf16*)a1n,
                          (const bf16*)fcw, (bf16*)out,
                          xs, hs, xbar, attnT, part, hroot, b, tid);
}

extern "C" void kernel_launch(void* const* d_in, const int* in_sizes, int n_in,
                              void* d_out, int out_size, void* d_ws, size_t ws_size,
                              hipStream_t stream) {
    const int B = in_sizes[0] / 256;  // 1024
    // ws layout (floats): xbar0[B*11*1024] | hsws[B*11*512]  (~69.2 MB @ B=1024)
    const size_t ws_need = (size_t)B * 11 * 1536 * sizeof(float);

    if (d_ws && ws_size >= ws_need && ((B * 11) % 128) == 0 && (B % 4) == 0) {
        float* xbar0 = (float*)d_ws;
        float* hsws  = xbar0 + (size_t)B * 11 * 1024;
        gat_agg0v5<<<B * 11, 256, 0, stream>>>(d_in[0], d_in[1], d_in[2],
                                               d_in[4], d_in[5], xbar0);
        gat_gemm0<<<(B * 11 / 128) * 4, 256, 0, stream>>>(d_in[0], xbar0,
                                                          d_in[3], hsws);
        gat_root3<<<B / 4, 256, 0, stream>>>(d_in[0], hsws, d_in[6], d_in[7],
                                             d_in[8], d_in[9], d_out);
    } else {
        gat_fused<<<B, 256, 0, stream>>>(d_in[0], d_in[1], d_in[2], d_in[3],
                                         d_in[4], d_in[5], d_in[6], d_in[7],
                                         d_in[8], d_in[9], d_out);
    }
}

// Round 9
// 548.919 us; speedup vs baseline: 1.0588x; 1.0588x over previous
//
#include <hip/hip_runtime.h>
#include <hip/hip_bf16.h>

#define NEG_SLOPE 0.2f

using bf16 = __hip_bfloat16;

__device__ __forceinline__ float tof(bf16 v) { return __bfloat162float(v); }
__device__ __forceinline__ float tof(float v) { return v; }
__device__ __forceinline__ void store_val(bf16* p, float v) { *p = __float2bfloat16(v); }
__device__ __forceinline__ void store_val(float* p, float v) { *p = v; }

// load 8 consecutive elems of T from GLOBAL as fp32 (16B bf16 / 32B fp32)
template <typename T>
__device__ __forceinline__ void load8(const T* p, float* o) {
    if constexpr (sizeof(T) == 2) {
        uint4 raw = *(const uint4*)p;
        const bf16* h = (const bf16*)&raw;
#pragma unroll
        for (int k = 0; k < 8; ++k) o[k] = tof(h[k]);
    } else {
        float4 r0 = *(const float4*)p;
        float4 r1 = *(const float4*)(p + 4);
        o[0] = r0.x; o[1] = r0.y; o[2] = r0.z; o[3] = r0.w;
        o[4] = r1.x; o[5] = r1.y; o[6] = r1.z; o[7] = r1.w;
    }
}

// load 8 consecutive elems of T from LDS as fp32 (8B-aligned ok for bf16)
template <typename T>
__device__ __forceinline__ void lds8(const T* p, float* o) {
    if constexpr (sizeof(T) == 2) {
        uint2 r0 = *(const uint2*)p;
        uint2 r1 = *(const uint2*)(p + 4);
        const bf16* h0 = (const bf16*)&r0;
        const bf16* h1 = (const bf16*)&r1;
#pragma unroll
        for (int k = 0; k < 4; ++k) { o[k] = tof(h0[k]); o[4 + k] = tof(h1[k]); }
    } else {
        float4 r0 = *(const float4*)p;
        float4 r1 = *(const float4*)(p + 4);
        o[0] = r0.x; o[1] = r0.y; o[2] = r0.z; o[3] = r0.w;
        o[4] = r1.x; o[5] = r1.y; o[6] = r1.z; o[7] = r1.w;
    }
}

// Parallel dtype detect via ballot (validated r6-r8).
__device__ __forceinline__ int detect_ballot(const void* x0, int tid, int* flag4) {
    bool bad = false;
    if (tid < 128) {
        unsigned short u = ((const unsigned short*)x0)[tid];
        float v = __uint_as_float(((unsigned int)u) << 16);
        bad = !(fabsf(v) < 100.f);   // catches NaN too
    }
    unsigned long long m = __ballot(bad);
    if ((tid & 63) == 0) flag4[tid >> 6] = (m != 0ULL);
    __syncthreads();
    return flag4[0] | flag4[1] | flag4[2] | flag4[3];
}

// Stage NS rows x 256 elems RAW (native dtype) into LDS, row stride 260 elems.
// fp32: uint4 writes (row 1040 B, 16B-aligned). bf16: uint2 pairs (row 520 B).
template <typename T, int NS>
__device__ __forceinline__ void stage_raw(T* xs, const T* self, const T* neigh, int tid) {
    constexpr int V = 16 / sizeof(T);
    constexpr int TOT = NS * 256 / V;
    for (int i = tid; i < TOT; i += 256) {
        int e = i * V;
        int s = e >> 8, f = e & 255;
        const T* src = (s == 0) ? (self + f) : (neigh + (size_t)(s - 1) * 256 + f);
        uint4 raw = *(const uint4*)src;    // 16B coalesced
        T* d = &xs[s * 260 + f];
        if constexpr (sizeof(T) == 2) {
            *(uint2*)d = make_uint2(raw.x, raw.y);
            *(uint2*)(d + 4) = make_uint2(raw.z, raw.w);
        } else {
            *(uint4*)d = raw;
        }
    }
}

// Level-0 attention over native-dtype LDS tile (F=256, stride 260 elems).
// Same validated thread map as attention2: tid = half*128 + grp*32 + u.
template <typename T, int NS>
__device__ __forceinline__ void attention_s(const T* xs, const T* a_self,
                                            const T* a_neigh, float (*attnT)[4],
                                            float* part, int tid) {
    const int half = tid >> 7;
    const int grp  = (tid >> 5) & 3;
    const int u    = tid & 31;
    float val = 0.f;
    if (u <= NS) {
        const T* a = ((u < NS) ? a_neigh : a_self) + (size_t)grp * 256;
        const T* xrow = xs + (size_t)(u < NS ? u : 0) * 260;
        const int f0 = half * 128;
        float s0 = 0.f, s1 = 0.f, s2 = 0.f, s3 = 0.f;
        float s4 = 0.f, s5 = 0.f, s6 = 0.f, s7 = 0.f;
#pragma unroll 2
        for (int f = f0; f < f0 + 128; f += 8) {
            float av[8], xv[8];
            load8(a + f, av);
            lds8(xrow + f, xv);
            s0 += xv[0] * av[0]; s1 += xv[1] * av[1];
            s2 += xv[2] * av[2]; s3 += xv[3] * av[3];
            s4 += xv[4] * av[4]; s5 += xv[5] * av[5];
            s6 += xv[6] * av[6]; s7 += xv[7] * av[7];
        }
        val = ((s0 + s1) + (s2 + s3)) + ((s4 + s5) + (s6 + s7));
    }
    part[tid] = val;
    __syncthreads();
    if (half == 0) {
        float v = part[tid] + part[tid + 128];
        float ls = __shfl(v, NS, 32);
        float x = -1e30f;
        if (u < NS) {
            float t = ls + v;
            x = (t > 0.f) ? t : NEG_SLOPE * t;
        }
        float m = x;
#pragma unroll
        for (int off = 16; off; off >>= 1) m = fmaxf(m, __shfl_xor(m, off, 32));
        float e = (u < NS) ? __expf(x - m) : 0.f;
        float s = e;
#pragma unroll
        for (int off = 16; off; off >>= 1) s += __shfl_xor(s, off, 32);
        if (u < NS) attnT[u][grp] = e / s;
    }
    __syncthreads();
}

// aggregate: thread = feature column, native-dtype LDS read + convert.
template <typename T, int NS>
__device__ __forceinline__ void agg_store_s(const T* xs, const float (*attnT)[4],
                                            float* dst, int tid) {
    float a0 = 0.f, a1 = 0.f, a2 = 0.f, a3 = 0.f;
#pragma unroll
    for (int s = 0; s < NS; ++s) {
        float4 w = *(const float4*)attnT[s];   // uniform -> broadcast
        float xv = tof(xs[(size_t)s * 260 + tid]);
        a0 += w.x * xv; a1 += w.y * xv; a2 += w.z * xv; a3 += w.w * xv;
    }
    dst[tid] = a0; dst[256 + tid] = a1; dst[512 + tid] = a2; dst[768 + tid] = a3;
}

// ===================== Kernel 1: level-0 attn+agg, dtype-specialized ========
// Two instantiations launched back-to-back; each early-exits on dtype
// mismatch (cheap: one L2-hot 256B load + ballot). bf16 instantiation has
// 13.5 KB xs -> ~15.3 KB LDS -> 8 blocks/CU (vs 5 for fp32's 28.5 KB).
template <typename T>
__global__ __launch_bounds__(256) void gat_agg0t(
    const void* x0, const void* x1, const void* x2,
    const void* a0s, const void* a0n, float* xbar0)
{
    const int node = blockIdx.x % 11;
    const int b = blockIdx.x / 11;
    const int tid = threadIdx.x;
    __shared__ __align__(16) T xs[26 * 260];
    __shared__ __align__(16) float attnT[26][4];
    __shared__ float part[256];
    __shared__ int flag4[4];

    const int is32 = detect_ballot(x0, tid, flag4);
    constexpr bool WANT32 = (sizeof(T) == 4);
    if ((is32 != 0) != WANT32) return;   // uniform branch, no barriers after

    const T* X0 = (const T*)x0;
    const T* X1 = (const T*)x1;
    const T* X2 = (const T*)x2;
    const T* As = (const T*)a0s;
    const T* An = (const T*)a0n;
    float* dst = xbar0 + (size_t)blockIdx.x * 1024;

    if (node == 0) {
        stage_raw<T, 11>(xs, X0 + (size_t)b * 256, X1 + (size_t)b * 2560, tid);
        __syncthreads();
        attention_s<T, 11>(xs, As, An, attnT, part, tid);
        agg_store_s<T, 11>(xs, attnT, dst, tid);
    } else {
        int p = node - 1;
        stage_raw<T, 26>(xs, X1 + ((size_t)b * 10 + p) * 256,
                         X2 + ((size_t)b * 250 + (size_t)p * 25) * 256, tid);
        __syncthreads();
        attention_s<T, 26>(xs, As, An, attnT, part, tid);
        agg_store_s<T, 26>(xs, attnT, dst, tid);
    }
}

// ---- wave-parallel logits + softmax on fp32 LDS (validated; root3/fallback)
template <typename T, int F, int NS, int FP>
__device__ __forceinline__ void attention2(const float* xs, const T* a_self,
                                           const T* a_neigh, float (*attnT)[4],
                                           float* part, int tid) {
    const int half = tid >> 7;
    const int grp  = (tid >> 5) & 3;
    const int u    = tid & 31;
    float val = 0.f;
    if (u <= NS) {
        const T* a = ((u < NS) ? a_neigh : a_self) + (size_t)grp * F;
        const float* xrow = xs + (size_t)(u < NS ? u : 0) * FP;
        const int f0 = half * (F / 2);
        float s0 = 0.f, s1 = 0.f, s2 = 0.f, s3 = 0.f;
        float s4 = 0.f, s5 = 0.f, s6 = 0.f, s7 = 0.f;
#pragma unroll 2
        for (int f = f0; f < f0 + F / 2; f += 8) {
            float av[8];
            load8(a + f, av);
            float4 x0 = *(const float4*)(xrow + f);
            float4 x1 = *(const float4*)(xrow + f + 4);
            s0 += x0.x * av[0]; s1 += x0.y * av[1];
            s2 += x0.z * av[2]; s3 += x0.w * av[3];
            s4 += x1.x * av[4]; s5 += x1.y * av[5];
            s6 += x1.z * av[6]; s7 += x1.w * av[7];
        }
        val = ((s0 + s1) + (s2 + s3)) + ((s4 + s5) + (s6 + s7));
    }
    part[tid] = val;
    __syncthreads();
    if (half == 0) {
        float v = part[tid] + part[tid + 128];
        float ls = __shfl(v, NS, 32);
        float x = -1e30f;
        if (u < NS) {
            float t = ls + v;
            x = (t > 0.f) ? t : NEG_SLOPE * t;
        }
        float m = x;
#pragma unroll
        for (int off = 16; off; off >>= 1) m = fmaxf(m, __shfl_xor(m, off, 32));
        float e = (u < NS) ? __expf(x - m) : 0.f;
        float s = e;
#pragma unroll
        for (int off = 16; off; off >>= 1) s += __shfl_xor(s, off, 32);
        if (u < NS) attnT[u][grp] = e / s;
    }
    __syncthreads();
}

// ===================== Kernel 2: level-0 transform GEMM (r3/r7-proven) ======
// Y[n][ht*128 + d] = sum_k X[n][ht*256 + k] * W[ht][k][d]
// Tile 64 rows x 128 cols, K chunks of 32 in LDS (X pad 36, W pad 132).
template <typename T>
__device__ __forceinline__ void gemm0_body(
    const float* __restrict__ X, const T* __restrict__ W, float* __restrict__ Y,
    float* xbt, float* wt, int bid, int tid)
{
    constexpr int MT = 64, KC = 32, MR = 4;
    const int ht = bid % 4;
    const int mt = bid / 4;
    const int n0 = mt * MT;
    const int tx = tid & 15;
    const int ty = tid >> 4;

    const float* Xb = X + (size_t)n0 * 1024 + (size_t)ht * 256;
    const T* Wb = W + (size_t)ht * 256 * 128;

    float acc[MR][8];
#pragma unroll
    for (int m = 0; m < MR; ++m)
#pragma unroll
        for (int d = 0; d < 8; ++d) acc[m][d] = 0.f;

    for (int kc = 0; kc < 256; kc += KC) {
        __syncthreads();
        for (int i = tid; i < MT * KC / 4; i += 256) {
            int r = i >> 3;
            int c = (i & 7) << 2;
            *(float4*)&xbt[r * 36 + c] = *(const float4*)(Xb + (size_t)r * 1024 + kc + c);
        }
        for (int i = tid; i < KC * 16; i += 256) {
            int r = i >> 4, c = (i & 15) << 3;
            float tmp[8];
            load8(Wb + (size_t)(kc + r) * 128 + c, tmp);
            *(float4*)&wt[r * 132 + c] = make_float4(tmp[0], tmp[1], tmp[2], tmp[3]);
            *(float4*)&wt[r * 132 + c + 4] = make_float4(tmp[4], tmp[5], tmp[6], tmp[7]);
        }
        __syncthreads();
#pragma unroll 2
        for (int k = 0; k < KC; k += 4) {
            float4 xv[MR];
#pragma unroll
            for (int m = 0; m < MR; ++m)
                xv[m] = *(const float4*)&xbt[(ty * MR + m) * 36 + k];
#pragma unroll
            for (int kk = 0; kk < 4; ++kk) {
                float wv[8];
                *(float4*)&wv[0] = *(const float4*)&wt[(k + kk) * 132 + tx * 8];
                *(float4*)&wv[4] = *(const float4*)&wt[(k + kk) * 132 + tx * 8 + 4];
#pragma unroll
                for (int m = 0; m < MR; ++m) {
                    float xsv = (kk == 0) ? xv[m].x : (kk == 1) ? xv[m].y
                              : (kk == 2) ? xv[m].z : xv[m].w;
#pragma unroll
                    for (int d = 0; d < 8; ++d) acc[m][d] += xsv * wv[d];
                }
            }
        }
    }
#pragma unroll
    for (int m = 0; m < MR; ++m) {
        float* yp = Y + (size_t)(n0 + ty * MR + m) * 512 + ht * 128 + tx * 8;
        *(float4*)(yp + 0) = make_float4(acc[m][0], acc[m][1], acc[m][2], acc[m][3]);
        *(float4*)(yp + 4) = make_float4(acc[m][4], acc[m][5], acc[m][6], acc[m][7]);
    }
}

__global__ __launch_bounds__(256) void gat_gemm0(
    const void* x0, const float* X, const void* W, float* Y)
{
    __shared__ __align__(16) float xbt[64 * 36];
    __shared__ __align__(16) float wt[32 * 132];
    __shared__ int flag4[4];
    const int tid = threadIdx.x;
    if (detect_ballot(x0, tid, flag4))
        gemm0_body<float>(X, (const float*)W, Y, xbt, wt, blockIdx.x, tid);
    else
        gemm0_body<bf16>(X, (const bf16*)W, Y, xbt, wt, blockIdx.x, tid);
}

// ===================== Kernel 3: root layer, G=4 per block (r7-proven) ======
template <typename T>
__device__ __forceinline__ void root3_body(
    const float* hsws, const T* w1, const T* a1s, const T* a1n, const T* fcw,
    T* out, float* hs, float* xbarAll, float (*attnT)[4], float* part,
    int b0, int tid)
{
    for (int g = 0; g < 4; ++g) {
        int b = b0 + g;
        for (int i = tid; i < 11 * 128; i += 256) {
            int s = i >> 7, f = (i & 127) << 2;
            *(float4*)&hs[s * 516 + f] =
                *(const float4*)(hsws + ((size_t)b * 11 + s) * 512 + f);
        }
        __syncthreads();
        attention2<T, 512, 11, 516>(hs, a1s, a1n, attnT, part, tid);
        float* xbar = xbarAll + g * 2080;
        {
            float a00=0,a01=0,a10=0,a11=0,a20=0,a21=0,a30=0,a31=0;
#pragma unroll
            for (int s = 0; s < 11; ++s) {
                float4 w = *(const float4*)attnT[s];
                float xv0 = hs[s * 516 + tid], xv1 = hs[s * 516 + tid + 256];
                a00 += w.x * xv0; a01 += w.x * xv1;
                a10 += w.y * xv0; a11 += w.y * xv1;
                a20 += w.z * xv0; a21 += w.z * xv1;
                a30 += w.w * xv0; a31 += w.w * xv1;
            }
            int k0 = tid, k1 = tid + 256;
            int o0 = k0 + (k0 >> 7), o1 = k1 + (k1 >> 7);
            xbar[0 * 520 + o0] = a00; xbar[0 * 520 + o1] = a01;
            xbar[1 * 520 + o0] = a10; xbar[1 * 520 + o1] = a11;
            xbar[2 * 520 + o0] = a20; xbar[2 * 520 + o1] = a21;
            xbar[3 * 520 + o0] = a30; xbar[3 * 520 + o1] = a31;
        }
        __syncthreads();
    }

    {
        const int q = tid & 3, g2 = tid >> 2;
        const int h = g2 >> 4, d0 = (g2 & 15) * 8;
        const T* wp = w1 + (size_t)h * 512 * 128 + d0;
        float acc[4][8];
#pragma unroll
        for (int g = 0; g < 4; ++g)
#pragma unroll
            for (int j = 0; j < 8; ++j) acc[g][j] = 0.f;
#pragma unroll 2
        for (int i = 0; i < 128; ++i) {
            float wv[8];
            load8(wp + (size_t)(q * 128 + i) * 128, wv);
#pragma unroll
            for (int g = 0; g < 4; ++g) {
                float xv = xbarAll[g * 2080 + h * 520 + q * 129 + i];
#pragma unroll
                for (int j = 0; j < 8; ++j) acc[g][j] += xv * wv[j];
            }
        }
        __syncthreads();
        float* red = xbarAll;
#pragma unroll
        for (int g = 0; g < 4; ++g) {
            float* r = &red[(q * 64 + g2) * 33 + g * 8];
            *(float4*)(r + 0) = make_float4(acc[g][0], acc[g][1], acc[g][2], acc[g][3]);
            *(float4*)(r + 4) = make_float4(acc[g][4], acc[g][5], acc[g][6], acc[g][7]);
        }
    }
    __syncthreads();
    {
        const int g = tid & 3, t = tid >> 2;
        float s8[8] = {0,0,0,0,0,0,0,0};
#pragma unroll
        for (int q2 = 0; q2 < 4; ++q2) {
            const float* rr = &xbarAll[(q2 * 64 + t) * 33 + g * 8];
            float4 p0 = *(const float4*)rr, p1 = *(const float4*)(rr + 4);
            s8[0] += p0.x; s8[1] += p0.y; s8[2] += p0.z; s8[3] += p0.w;
            s8[4] += p1.x; s8[5] += p1.y; s8[6] += p1.z; s8[7] += p1.w;
        }
        int f0 = (t >> 4) * 128 + (t & 15) * 8;
        float* hp = &hs[g * 545 + f0 + 4 * (f0 >> 6)];
        *(float4*)(hp + 0) = make_float4(s8[0], s8[1], s8[2], s8[3]);
        *(float4*)(hp + 4) = make_float4(s8[4], s8[5], s8[6], s8[7]);
    }
    __syncthreads();
    {
        const int fq = tid >> 5, jb = tid & 31;
        float acc[4][8];
#pragma unroll
        for (int g = 0; g < 4; ++g)
#pragma unroll
            for (int j = 0; j < 8; ++j) acc[g][j] = 0.f;
#pragma unroll 2
        for (int i = 0; i < 64; ++i) {
            float wv[8];
            load8(fcw + (size_t)(fq * 64 + i) * 256 + jb * 8, wv);
#pragma unroll
            for (int g = 0; g < 4; ++g) {
                float xv = hs[g * 545 + fq * 68 + i];
#pragma unroll
                for (int j = 0; j < 8; ++j) acc[g][j] += xv * wv[j];
            }
        }
        __syncthreads();
        float* red2 = xbarAll;
#pragma unroll
        for (int g = 0; g < 4; ++g) {
            float* r = &red2[(fq * 32 + jb) * 33 + g * 8];
            *(float4*)(r + 0) = make_float4(acc[g][0], acc[g][1], acc[g][2], acc[g][3]);
            *(float4*)(r + 4) = make_float4(acc[g][4], acc[g][5], acc[g][6], acc[g][7]);
        }
    }
    __syncthreads();
    if (tid < 128) {
        const int g = tid >> 5, jb = tid & 31;
        float s8[8] = {0,0,0,0,0,0,0,0};
#pragma unroll
        for (int q2 = 0; q2 < 8; ++q2) {
            const float* rr = &xbarAll[(q2 * 32 + jb) * 33 + g * 8];
            float4 p0 = *(const float4*)rr, p1 = *(const float4*)(rr + 4);
            s8[0] += p0.x; s8[1] += p0.y; s8[2] += p0.z; s8[3] += p0.w;
            s8[4] += p1.x; s8[5] += p1.y; s8[6] += p1.z; s8[7] += p1.w;
        }
        T* op = out + (size_t)(b0 + g) * 256 + jb * 8;
#pragma unroll
        for (int j = 0; j < 8; ++j) store_val(op + j, s8[j]);
    }
}

__global__ __launch_bounds__(256) void gat_root3(
    const void* x0, const float* hsws, const void* w1, const void* a1s,
    const void* a1n, const void* fcw, void* out)
{
    const int b0 = blockIdx.x * 4;
    const int tid = threadIdx.x;
    __shared__ __align__(16) float hs[11 * 516];
    __shared__ __align__(16) float xbarAll[8448];
    __shared__ __align__(16) float attnT[26][4];
    __shared__ float part[256];
    __shared__ int flag4[4];
    if (detect_ballot(x0, tid, flag4))
        root3_body<float>(hsws, (const float*)w1, (const float*)a1s,
                          (const float*)a1n, (const float*)fcw, (float*)out,
                          hs, xbarAll, attnT, part, b0, tid);
    else
        root3_body<bf16>(hsws, (const bf16*)w1, (const bf16*)a1s,
                         (const bf16*)a1n, (const bf16*)fcw, (bf16*)out,
                         hs, xbarAll, attnT, part, b0, tid);
}

// ================= Fallback: fully-fused single kernel (ws-less) ============
template <typename T, int F, int NS, int FP>
__device__ __forceinline__ void stage(float* xs, const T* self, const T* neigh, int tid) {
    constexpr int V = 16 / sizeof(T);
    constexpr int TOT = NS * F / V;
    for (int i = tid; i < TOT; i += 256) {
        int e = i * V;
        int s = e / F, f = e % F;
        const T* src = (s == 0) ? (self + f) : (neigh + (size_t)(s - 1) * F + f);
        uint4 raw = *(const uint4*)src;
        const T* hv = (const T*)&raw;
        float* dst = &xs[s * FP + f];
#pragma unroll
        for (int k = 0; k < V; ++k) dst[k] = tof(hv[k]);
    }
}

template <int F, int NS, int FP>
__device__ __forceinline__ void aggregate2(const float* xs, const float (*attnT)[4],
                                           float* xbar, int tid) {
    constexpr int FCH = F / 256;
    float acc[4][FCH];
#pragma unroll
    for (int h = 0; h < 4; ++h)
#pragma unroll
        for (int c = 0; c < FCH; ++c) acc[h][c] = 0.f;
#pragma unroll
    for (int s = 0; s < NS; ++s) {
        float4 w = *(const float4*)attnT[s];
#pragma unroll
        for (int c = 0; c < FCH; ++c) {
            float xv = xs[(size_t)s * FP + tid + c * 256];
            acc[0][c] += w.x * xv;
            acc[1][c] += w.y * xv;
            acc[2][c] += w.z * xv;
            acc[3][c] += w.w * xv;
        }
    }
#pragma unroll
    for (int c = 0; c < FCH; ++c)
#pragma unroll
        for (int h = 0; h < 4; ++h)
            xbar[h * F + tid + c * 256] = acc[h][c];
}

template <typename T, int F>
__device__ __forceinline__ void transform_o(const float* xbar, const T* w,
                                            float* dst, int tid) {
#pragma unroll
    for (int r = 0; r < 2; ++r) {
        int o = tid + r * 256;
        int h = o >> 7, d = o & 127;
        const T* wp = w + (size_t)h * F * 128 + d;
        const float* xb = xbar + (size_t)h * F;
        float a0 = 0.f, a1 = 0.f, a2 = 0.f, a3 = 0.f;
        for (int f = 0; f < F; f += 4) {
            a0 += xb[f + 0] * tof(wp[(size_t)(f + 0) * 128]);
            a1 += xb[f + 1] * tof(wp[(size_t)(f + 1) * 128]);
            a2 += xb[f + 2] * tof(wp[(size_t)(f + 2) * 128]);
            a3 += xb[f + 3] * tof(wp[(size_t)(f + 3) * 128]);
        }
        dst[o] = (a0 + a1) + (a2 + a3);
    }
}

template <typename T>
__device__ __forceinline__ void gat_body_fb(
    const T* x0, const T* x1, const T* x2, const T* w0, const T* a0s,
    const T* a0n, const T* w1, const T* a1s, const T* a1n, const T* fcw,
    T* out, float* xs, float* hs, float* xbar, float (*attnT)[4],
    float* part, float* hroot, int b, int tid)
{
    for (int p = 0; p < 10; ++p) {
        stage<T, 256, 26, 260>(xs, x1 + ((size_t)b * 10 + p) * 256,
                               x2 + ((size_t)b * 250 + (size_t)p * 25) * 256, tid);
        __syncthreads();
        attention2<T, 256, 26, 260>(xs, a0s, a0n, attnT, part, tid);
        aggregate2<256, 26, 260>(xs, attnT, xbar, tid);
        __syncthreads();
        transform_o<T, 256>(xbar, w0, &hs[(p + 1) * 516], tid);
        __syncthreads();
    }
    stage<T, 256, 11, 260>(xs, x0 + (size_t)b * 256, x1 + (size_t)b * 2560, tid);
    __syncthreads();
    attention2<T, 256, 11, 260>(xs, a0s, a0n, attnT, part, tid);
    aggregate2<256, 11, 260>(xs, attnT, xbar, tid);
    __syncthreads();
    transform_o<T, 256>(xbar, w0, &hs[0], tid);
    __syncthreads();
    attention2<T, 512, 11, 516>(hs, a1s, a1n, attnT, part, tid);
    aggregate2<512, 11, 516>(hs, attnT, xbar, tid);
    __syncthreads();
    transform_o<T, 512>(xbar, w1, hroot, tid);
    __syncthreads();
    const T* fp = fcw + tid;
    float a0 = 0.f, a1 = 0.f, a2 = 0.f, a3 = 0.f;
    for (int f = 0; f < 512; f += 4) {
        a0 += hroot[f + 0] * tof(fp[(size_t)(f + 0) * 256]);
        a1 += hroot[f + 1] * tof(fp[(size_t)(f + 1) * 256]);
        a2 += hroot[f + 2] * tof(fp[(size_t)(f + 2) * 256]);
        a3 += hroot[f + 3] * tof(fp[(size_t)(f + 3) * 256]);
    }
    store_val(&out[(size_t)b * 256 + tid], (a0 + a1) + (a2 + a3));
}

__global__ __launch_bounds__(256) void gat_fused(
    const void* x0, const void* x1, const void* x2, const void* w0,
    const void* a0s, const void* a0n, const void* w1, const void* a1s,
    const void* a1n, const void* fcw, void* out)
{
    const int b = blockIdx.x;
    const int tid = threadIdx.x;
    __shared__ __align__(16) float xs[26 * 260];
    __shared__ __align__(16) float hs[11 * 516];
    __shared__ __align__(16) float xbar[4 * 512];
    __shared__ __align__(16) float attnT[26][4];
    __shared__ float part[256];
    __shared__ __align__(16) float hroot[512];
    __shared__ int flag4[4];
    if (detect_ballot(x0, tid, flag4))
        gat_body_fb<float>((const float*)x0, (const float*)x1, (const float*)x2,
                           (const float*)w0, (const float*)a0s, (const float*)a0n,
                           (const float*)w1, (const float*)a1s, (const float*)a1n,
                           (const float*)fcw, (float*)out,
                           xs, hs, xbar, attnT, part, hroot, b, tid);
    else
        gat_body_fb<bf16>((const bf16*)x0, (const bf16*)x1, (const bf16*)x2,
                          (const bf16*)w0, (const bf16*)a0s, (const bf16*)a0n,
                          (const bf16*)w1, (const bf16*)a1s, (const bf16*)a1n,
                          (const bf16*)fcw, (bf16*)out,
                          xs, hs, xbar, attnT, part, hroot, b, tid);
}

extern "C" void kernel_launch(void* const* d_in, const int* in_sizes, int n_in,
                              void* d_out, int out_size, void* d_ws, size_t ws_size,
                              hipStream_t stream) {
    const int B = in_sizes[0] / 256;  // 1024
    // ws layout (floats): xbar0[B*11*1024] | hsws[B*11*512]  (~69.2 MB @ B=1024)
    const size_t ws_need = (size_t)B * 11 * 1536 * sizeof(float);

    if (d_ws && ws_size >= ws_need && ((B * 11) % 64) == 0 && (B % 4) == 0) {
        float* xbar0 = (float*)d_ws;
        float* hsws  = xbar0 + (size_t)B * 11 * 1024;
        // dtype-specialized agg0: each instance early-exits on mismatch.
        gat_agg0t<bf16><<<B * 11, 256, 0, stream>>>(d_in[0], d_in[1], d_in[2],
                                                    d_in[4], d_in[5], xbar0);
        gat_agg0t<float><<<B * 11, 256, 0, stream>>>(d_in[0], d_in[1], d_in[2],
                                                     d_in[4], d_in[5], xbar0);
        gat_gemm0<<<(B * 11 / 64) * 4, 256, 0, stream>>>(d_in[0], xbar0,
                                                         d_in[3], hsws);
        gat_root3<<<B / 4, 256, 0, stream>>>(d_in[0], hsws, d_in[6], d_in[7],
                                             d_in[8], d_in[9], d_out);
    } else {
        gat_fused<<<B, 256, 0, stream>>>(d_in[0], d_in[1], d_in[2], d_in[3],
                                         d_in[4], d_in[5], d_in[6], d_in[7],
                                         d_in[8], d_in[9], d_out);
    }
}

// Round 10
// 525.850 us; speedup vs baseline: 1.1052x; 1.0439x over previous
//
#include <hip/hip_runtime.h>
#include <hip/hip_bf16.h>

#define NEG_SLOPE 0.2f

using bf16 = __hip_bfloat16;

__device__ __forceinline__ float tof(bf16 v) { return __bfloat162float(v); }
__device__ __forceinline__ float tof(float v) { return v; }
__device__ __forceinline__ void store_val(bf16* p, float v) { *p = __float2bfloat16(v); }
__device__ __forceinline__ void store_val(float* p, float v) { *p = v; }

// load 8 consecutive elems of T as fp32 (16B bf16 / 32B fp32)
template <typename T>
__device__ __forceinline__ void load8(const T* p, float* o) {
    if constexpr (sizeof(T) == 2) {
        uint4 raw = *(const uint4*)p;
        const bf16* h = (const bf16*)&raw;
#pragma unroll
        for (int k = 0; k < 8; ++k) o[k] = tof(h[k]);
    } else {
        float4 r0 = *(const float4*)p;
        float4 r1 = *(const float4*)(p + 4);
        o[0] = r0.x; o[1] = r0.y; o[2] = r0.z; o[3] = r0.w;
        o[4] = r1.x; o[5] = r1.y; o[6] = r1.z; o[7] = r1.w;
    }
}

// load 4 consecutive fp32 (16B)
__device__ __forceinline__ void load4f(const float* p, float* o) {
    float4 r = *(const float4*)p;
    o[0] = r.x; o[1] = r.y; o[2] = r.z; o[3] = r.w;
}

// Parallel dtype detect via ballot (validated r6-r9).
__device__ __forceinline__ int detect_ballot(const void* x0, int tid, int* flag4) {
    bool bad = false;
    if (tid < 128) {
        unsigned short u = ((const unsigned short*)x0)[tid];
        float v = __uint_as_float(((unsigned int)u) << 16);
        bad = !(fabsf(v) < 100.f);   // catches NaN too
    }
    unsigned long long m = __ballot(bad);
    if ((tid & 63) == 0) flag4[tid >> 6] = (m != 0ULL);
    __syncthreads();
    return flag4[0] | flag4[1] | flag4[2] | flag4[3];
}

// ===================== Kernel 1: level-0 attn+agg, LDS-free, coalesced ======
// Thread (u = tid>>3, c = tid&7): u = sample row (0 = self; 31 = self-logit).
// Register ownership is COALESCED: fp32 f = j*32 + c*4 (8-lane group reads
// 128B contiguous per float4); bf16 f = j*64 + c*8 (128B per load8 group).
// Dot partials for all 4 heads from registers (a from L1). part2[u*36+c*4]
// (measured-cheap conflicts, r6: ~5us). Aggregate re-reads x from global,
// thread = column, fully coalesced, L3-hot (v4-measured: FETCH unchanged).
template <typename T, int NS>
__device__ __forceinline__ void agg0v6_core(
    const T* self, const T* neigh, const T* a_s, const T* a_n,
    float* dst, float* part2, float* attnT, int tid)
{
    const int u = tid >> 3, c = tid & 7;
    if (u < NS || u == 31) {
        const bool sl = (u == 31);
        const T* src = (sl || u == 0) ? self : (neigh + (size_t)(u - 1) * 256);
        const T* a = sl ? a_s : a_n;
        float acc0 = 0.f, acc1 = 0.f, acc2 = 0.f, acc3 = 0.f;
        if constexpr (sizeof(T) == 2) {
#pragma unroll
            for (int j = 0; j < 4; ++j) {
                const int f = j * 64 + c * 8;
                float xv[8], av[8];
                load8(src + f, xv);
                load8(a + 0 * 256 + f, av);
#pragma unroll
                for (int k = 0; k < 8; ++k) acc0 += xv[k] * av[k];
                load8(a + 1 * 256 + f, av);
#pragma unroll
                for (int k = 0; k < 8; ++k) acc1 += xv[k] * av[k];
                load8(a + 2 * 256 + f, av);
#pragma unroll
                for (int k = 0; k < 8; ++k) acc2 += xv[k] * av[k];
                load8(a + 3 * 256 + f, av);
#pragma unroll
                for (int k = 0; k < 8; ++k) acc3 += xv[k] * av[k];
            }
        } else {
#pragma unroll
            for (int j = 0; j < 8; ++j) {
                const int f = j * 32 + c * 4;
                float xv[4], av[4];
                load4f((const float*)src + f, xv);
                load4f((const float*)a + 0 * 256 + f, av);
                acc0 += xv[0]*av[0] + xv[1]*av[1] + xv[2]*av[2] + xv[3]*av[3];
                load4f((const float*)a + 1 * 256 + f, av);
                acc1 += xv[0]*av[0] + xv[1]*av[1] + xv[2]*av[2] + xv[3]*av[3];
                load4f((const float*)a + 2 * 256 + f, av);
                acc2 += xv[0]*av[0] + xv[1]*av[1] + xv[2]*av[2] + xv[3]*av[3];
                load4f((const float*)a + 3 * 256 + f, av);
                acc3 += xv[0]*av[0] + xv[1]*av[1] + xv[2]*av[2] + xv[3]*av[3];
            }
        }
        *(float4*)&part2[u * 36 + c * 4] = make_float4(acc0, acc1, acc2, acc3);
    }
    __syncthreads();
    // softmax: 128 threads = 32 samples x 4 heads, shuffle over 32-lane groups
    if (tid < 128) {
        const int su = tid & 31, h = tid >> 5;
        float v = 0.f;
        if (su < NS || su == 31) {
#pragma unroll
            for (int cc = 0; cc < 8; ++cc) v += part2[su * 36 + cc * 4 + h];
        }
        float ls = __shfl(v, 31, 32);   // self logit lives in lane 31
        float x = -1e30f;
        if (su < NS) { float t = ls + v; x = (t > 0.f) ? t : NEG_SLOPE * t; }
        float m = x;
#pragma unroll
        for (int off = 16; off; off >>= 1) m = fmaxf(m, __shfl_xor(m, off, 32));
        float e = (su < NS) ? __expf(x - m) : 0.f;
        float s = e;
#pragma unroll
        for (int off = 16; off; off >>= 1) s += __shfl_xor(s, off, 32);
        if (su < NS) attnT[su * 4 + h] = e / s;
    }
    __syncthreads();
    // aggregate: thread = feature column, x from global (coalesced, L3-hot)
    {
        float a0 = 0.f, a1 = 0.f, a2 = 0.f, a3 = 0.f;
#pragma unroll
        for (int s = 0; s < NS; ++s) {
            float4 w = *(const float4*)&attnT[s * 4];   // uniform -> broadcast
            float xv = tof((s == 0) ? self[tid]
                                    : neigh[(size_t)(s - 1) * 256 + tid]);
            a0 += w.x * xv; a1 += w.y * xv; a2 += w.z * xv; a3 += w.w * xv;
        }
        dst[tid] = a0; dst[256 + tid] = a1; dst[512 + tid] = a2; dst[768 + tid] = a3;
    }
}

__global__ __launch_bounds__(256) void gat_agg0v6(
    const void* x0, const void* x1, const void* x2,
    const void* a0s, const void* a0n, float* xbar0)
{
    const int node = blockIdx.x % 11;
    const int b = blockIdx.x / 11;
    const int tid = threadIdx.x;
    __shared__ __align__(16) float part2[32 * 36];   // 4608 B
    __shared__ __align__(16) float attnT[128];       // 512 B
    __shared__ int flag4[4];
    float* dst = xbar0 + (size_t)blockIdx.x * 1024;
    if (detect_ballot(x0, tid, flag4)) {
        const float *X0 = (const float*)x0, *X1 = (const float*)x1, *X2 = (const float*)x2;
        const float *As = (const float*)a0s, *An = (const float*)a0n;
        if (node == 0)
            agg0v6_core<float, 11>(X0 + (size_t)b * 256, X1 + (size_t)b * 2560,
                                   As, An, dst, part2, attnT, tid);
        else {
            int p = node - 1;
            agg0v6_core<float, 26>(X1 + ((size_t)b * 10 + p) * 256,
                                   X2 + ((size_t)b * 250 + (size_t)p * 25) * 256,
                                   As, An, dst, part2, attnT, tid);
        }
    } else {
        const bf16 *X0 = (const bf16*)x0, *X1 = (const bf16*)x1, *X2 = (const bf16*)x2;
        const bf16 *As = (const bf16*)a0s, *An = (const bf16*)a0n;
        if (node == 0)
            agg0v6_core<bf16, 11>(X0 + (size_t)b * 256, X1 + (size_t)b * 2560,
                                  As, An, dst, part2, attnT, tid);
        else {
            int p = node - 1;
            agg0v6_core<bf16, 26>(X1 + ((size_t)b * 10 + p) * 256,
                                  X2 + ((size_t)b * 250 + (size_t)p * 25) * 256,
                                  As, An, dst, part2, attnT, tid);
        }
    }
}

// ---- wave-parallel logits + softmax on fp32 LDS (validated; root3/fallback)
template <typename T, int F, int NS, int FP>
__device__ __forceinline__ void attention2(const float* xs, const T* a_self,
                                           const T* a_neigh, float (*attnT)[4],
                                           float* part, int tid) {
    const int half = tid >> 7;
    const int grp  = (tid >> 5) & 3;
    const int u    = tid & 31;
    float val = 0.f;
    if (u <= NS) {
        const T* a = ((u < NS) ? a_neigh : a_self) + (size_t)grp * F;
        const float* xrow = xs + (size_t)(u < NS ? u : 0) * FP;
        const int f0 = half * (F / 2);
        float s0 = 0.f, s1 = 0.f, s2 = 0.f, s3 = 0.f;
        float s4 = 0.f, s5 = 0.f, s6 = 0.f, s7 = 0.f;
#pragma unroll 2
        for (int f = f0; f < f0 + F / 2; f += 8) {
            float av[8];
            load8(a + f, av);
            float4 x0 = *(const float4*)(xrow + f);
            float4 x1 = *(const float4*)(xrow + f + 4);
            s0 += x0.x * av[0]; s1 += x0.y * av[1];
            s2 += x0.z * av[2]; s3 += x0.w * av[3];
            s4 += x1.x * av[4]; s5 += x1.y * av[5];
            s6 += x1.z * av[6]; s7 += x1.w * av[7];
        }
        val = ((s0 + s1) + (s2 + s3)) + ((s4 + s5) + (s6 + s7));
    }
    part[tid] = val;
    __syncthreads();
    if (half == 0) {
        float v = part[tid] + part[tid + 128];
        float ls = __shfl(v, NS, 32);
        float x = -1e30f;
        if (u < NS) {
            float t = ls + v;
            x = (t > 0.f) ? t : NEG_SLOPE * t;
        }
        float m = x;
#pragma unroll
        for (int off = 16; off; off >>= 1) m = fmaxf(m, __shfl_xor(m, off, 32));
        float e = (u < NS) ? __expf(x - m) : 0.f;
        float s = e;
#pragma unroll
        for (int off = 16; off; off >>= 1) s += __shfl_xor(s, off, 32);
        if (u < NS) attnT[u][grp] = e / s;
    }
    __syncthreads();
}

// ===================== Kernel 2: level-0 transform GEMM (r3/r7-proven) ======
template <typename T>
__device__ __forceinline__ void gemm0_body(
    const float* __restrict__ X, const T* __restrict__ W, float* __restrict__ Y,
    float* xbt, float* wt, int bid, int tid)
{
    constexpr int MT = 64, KC = 32, MR = 4;
    const int ht = bid % 4;
    const int mt = bid / 4;
    const int n0 = mt * MT;
    const int tx = tid & 15;
    const int ty = tid >> 4;

    const float* Xb = X + (size_t)n0 * 1024 + (size_t)ht * 256;
    const T* Wb = W + (size_t)ht * 256 * 128;

    float acc[MR][8];
#pragma unroll
    for (int m = 0; m < MR; ++m)
#pragma unroll
        for (int d = 0; d < 8; ++d) acc[m][d] = 0.f;

    for (int kc = 0; kc < 256; kc += KC) {
        __syncthreads();
        for (int i = tid; i < MT * KC / 4; i += 256) {
            int r = i >> 3;
            int c = (i & 7) << 2;
            *(float4*)&xbt[r * 36 + c] = *(const float4*)(Xb + (size_t)r * 1024 + kc + c);
        }
        for (int i = tid; i < KC * 16; i += 256) {
            int r = i >> 4, c = (i & 15) << 3;
            float tmp[8];
            load8(Wb + (size_t)(kc + r) * 128 + c, tmp);
            *(float4*)&wt[r * 132 + c] = make_float4(tmp[0], tmp[1], tmp[2], tmp[3]);
            *(float4*)&wt[r * 132 + c + 4] = make_float4(tmp[4], tmp[5], tmp[6], tmp[7]);
        }
        __syncthreads();
#pragma unroll 2
        for (int k = 0; k < KC; k += 4) {
            float4 xv[MR];
#pragma unroll
            for (int m = 0; m < MR; ++m)
                xv[m] = *(const float4*)&xbt[(ty * MR + m) * 36 + k];
#pragma unroll
            for (int kk = 0; kk < 4; ++kk) {
                float wv[8];
                *(float4*)&wv[0] = *(const float4*)&wt[(k + kk) * 132 + tx * 8];
                *(float4*)&wv[4] = *(const float4*)&wt[(k + kk) * 132 + tx * 8 + 4];
#pragma unroll
                for (int m = 0; m < MR; ++m) {
                    float xsv = (kk == 0) ? xv[m].x : (kk == 1) ? xv[m].y
                              : (kk == 2) ? xv[m].z : xv[m].w;
#pragma unroll
                    for (int d = 0; d < 8; ++d) acc[m][d] += xsv * wv[d];
                }
            }
        }
    }
#pragma unroll
    for (int m = 0; m < MR; ++m) {
        float* yp = Y + (size_t)(n0 + ty * MR + m) * 512 + ht * 128 + tx * 8;
        *(float4*)(yp + 0) = make_float4(acc[m][0], acc[m][1], acc[m][2], acc[m][3]);
        *(float4*)(yp + 4) = make_float4(acc[m][4], acc[m][5], acc[m][6], acc[m][7]);
    }
}

__global__ __launch_bounds__(256) void gat_gemm0(
    const void* x0, const float* X, const void* W, float* Y)
{
    __shared__ __align__(16) float xbt[64 * 36];
    __shared__ __align__(16) float wt[32 * 132];
    __shared__ int flag4[4];
    const int tid = threadIdx.x;
    if (detect_ballot(x0, tid, flag4))
        gemm0_body<float>(X, (const float*)W, Y, xbt, wt, blockIdx.x, tid);
    else
        gemm0_body<bf16>(X, (const bf16*)W, Y, xbt, wt, blockIdx.x, tid);
}

// ===================== Kernel 3: root layer, G=4 per block (r7-proven) ======
template <typename T>
__device__ __forceinline__ void root3_body(
    const float* hsws, const T* w1, const T* a1s, const T* a1n, const T* fcw,
    T* out, float* hs, float* xbarAll, float (*attnT)[4], float* part,
    int b0, int tid)
{
    for (int g = 0; g < 4; ++g) {
        int b = b0 + g;
        for (int i = tid; i < 11 * 128; i += 256) {
            int s = i >> 7, f = (i & 127) << 2;
            *(float4*)&hs[s * 516 + f] =
                *(const float4*)(hsws + ((size_t)b * 11 + s) * 512 + f);
        }
        __syncthreads();
        attention2<T, 512, 11, 516>(hs, a1s, a1n, attnT, part, tid);
        float* xbar = xbarAll + g * 2080;
        {
            float a00=0,a01=0,a10=0,a11=0,a20=0,a21=0,a30=0,a31=0;
#pragma unroll
            for (int s = 0; s < 11; ++s) {
                float4 w = *(const float4*)attnT[s];
                float xv0 = hs[s * 516 + tid], xv1 = hs[s * 516 + tid + 256];
                a00 += w.x * xv0; a01 += w.x * xv1;
                a10 += w.y * xv0; a11 += w.y * xv1;
                a20 += w.z * xv0; a21 += w.z * xv1;
                a30 += w.w * xv0; a31 += w.w * xv1;
            }
            int k0 = tid, k1 = tid + 256;
            int o0 = k0 + (k0 >> 7), o1 = k1 + (k1 >> 7);
            xbar[0 * 520 + o0] = a00; xbar[0 * 520 + o1] = a01;
            xbar[1 * 520 + o0] = a10; xbar[1 * 520 + o1] = a11;
            xbar[2 * 520 + o0] = a20; xbar[2 * 520 + o1] = a21;
            xbar[3 * 520 + o0] = a30; xbar[3 * 520 + o1] = a31;
        }
        __syncthreads();
    }

    {
        const int q = tid & 3, g2 = tid >> 2;
        const int h = g2 >> 4, d0 = (g2 & 15) * 8;
        const T* wp = w1 + (size_t)h * 512 * 128 + d0;
        float acc[4][8];
#pragma unroll
        for (int g = 0; g < 4; ++g)
#pragma unroll
            for (int j = 0; j < 8; ++j) acc[g][j] = 0.f;
#pragma unroll 2
        for (int i = 0; i < 128; ++i) {
            float wv[8];
            load8(wp + (size_t)(q * 128 + i) * 128, wv);
#pragma unroll
            for (int g = 0; g < 4; ++g) {
                float xv = xbarAll[g * 2080 + h * 520 + q * 129 + i];
#pragma unroll
                for (int j = 0; j < 8; ++j) acc[g][j] += xv * wv[j];
            }
        }
        __syncthreads();
        float* red = xbarAll;
#pragma unroll
        for (int g = 0; g < 4; ++g) {
            float* r = &red[(q * 64 + g2) * 33 + g * 8];
            *(float4*)(r + 0) = make_float4(acc[g][0], acc[g][1], acc[g][2], acc[g][3]);
            *(float4*)(r + 4) = make_float4(acc[g][4], acc[g][5], acc[g][6], acc[g][7]);
        }
    }
    __syncthreads();
    {
        const int g = tid & 3, t = tid >> 2;
        float s8[8] = {0,0,0,0,0,0,0,0};
#pragma unroll
        for (int q2 = 0; q2 < 4; ++q2) {
            const float* rr = &xbarAll[(q2 * 64 + t) * 33 + g * 8];
            float4 p0 = *(const float4*)rr, p1 = *(const float4*)(rr + 4);
            s8[0] += p0.x; s8[1] += p0.y; s8[2] += p0.z; s8[3] += p0.w;
            s8[4] += p1.x; s8[5] += p1.y; s8[6] += p1.z; s8[7] += p1.w;
        }
        int f0 = (t >> 4) * 128 + (t & 15) * 8;
        float* hp = &hs[g * 545 + f0 + 4 * (f0 >> 6)];
        *(float4*)(hp + 0) = make_float4(s8[0], s8[1], s8[2], s8[3]);
        *(float4*)(hp + 4) = make_float4(s8[4], s8[5], s8[6], s8[7]);
    }
    __syncthreads();
    {
        const int fq = tid >> 5, jb = tid & 31;
        float acc[4][8];
#pragma unroll
        for (int g = 0; g < 4; ++g)
#pragma unroll
            for (int j = 0; j < 8; ++j) acc[g][j] = 0.f;
#pragma unroll 2
        for (int i = 0; i < 64; ++i) {
            float wv[8];
            load8(fcw + (size_t)(fq * 64 + i) * 256 + jb * 8, wv);
#pragma unroll
            for (int g = 0; g < 4; ++g) {
                float xv = hs[g * 545 + fq * 68 + i];
#pragma unroll
                for (int j = 0; j < 8; ++j) acc[g][j] += xv * wv[j];
            }
        }
        __syncthreads();
        float* red2 = xbarAll;
#pragma unroll
        for (int g = 0; g < 4; ++g) {
            float* r = &red2[(fq * 32 + jb) * 33 + g * 8];
            *(float4*)(r + 0) = make_float4(acc[g][0], acc[g][1], acc[g][2], acc[g][3]);
            *(float4*)(r + 4) = make_float4(acc[g][4], acc[g][5], acc[g][6], acc[g][7]);
        }
    }
    __syncthreads();
    if (tid < 128) {
        const int g = tid >> 5, jb = tid & 31;
        float s8[8] = {0,0,0,0,0,0,0,0};
#pragma unroll
        for (int q2 = 0; q2 < 8; ++q2) {
            const float* rr = &xbarAll[(q2 * 32 + jb) * 33 + g * 8];
            float4 p0 = *(const float4*)rr, p1 = *(const float4*)(rr + 4);
            s8[0] += p0.x; s8[1] += p0.y; s8[2] += p0.z; s8[3] += p0.w;
            s8[4] += p1.x; s8[5] += p1.y; s8[6] += p1.z; s8[7] += p1.w;
        }
        T* op = out + (size_t)(b0 + g) * 256 + jb * 8;
#pragma unroll
        for (int j = 0; j < 8; ++j) store_val(op + j, s8[j]);
    }
}

__global__ __launch_bounds__(256) void gat_root3(
    const void* x0, const float* hsws, const void* w1, const void* a1s,
    const void* a1n, const void* fcw, void* out)
{
    const int b0 = blockIdx.x * 4;
    const int tid = threadIdx.x;
    __shared__ __align__(16) float hs[11 * 516];
    __shared__ __align__(16) float xbarAll[8448];
    __shared__ __align__(16) float attnT[26][4];
    __shared__ float part[256];
    __shared__ int flag4[4];
    if (detect_ballot(x0, tid, flag4))
        root3_body<float>(hsws, (const float*)w1, (const float*)a1s,
                          (const float*)a1n, (const float*)fcw, (float*)out,
                          hs, xbarAll, attnT, part, b0, tid);
    else
        root3_body<bf16>(hsws, (const bf16*)w1, (const bf16*)a1s,
                         (const bf16*)a1n, (const bf16*)fcw, (bf16*)out,
                         hs, xbarAll, attnT, part, b0, tid);
}

// ================= Fallback: fully-fused single kernel (ws-less) ============
template <typename T, int F, int NS, int FP>
__device__ __forceinline__ void stage(float* xs, const T* self, const T* neigh, int tid) {
    constexpr int V = 16 / sizeof(T);
    constexpr int TOT = NS * F / V;
    for (int i = tid; i < TOT; i += 256) {
        int e = i * V;
        int s = e / F, f = e % F;
        const T* src = (s == 0) ? (self + f) : (neigh + (size_t)(s - 1) * F + f);
        uint4 raw = *(const uint4*)src;
        const T* hv = (const T*)&raw;
        float* dst = &xs[s * FP + f];
#pragma unroll
        for (int k = 0; k < V; ++k) dst[k] = tof(hv[k]);
    }
}

template <int F, int NS, int FP>
__device__ __forceinline__ void aggregate2(const float* xs, const float (*attnT)[4],
                                           float* xbar, int tid) {
    constexpr int FCH = F / 256;
    float acc[4][FCH];
#pragma unroll
    for (int h = 0; h < 4; ++h)
#pragma unroll
        for (int c = 0; c < FCH; ++c) acc[h][c] = 0.f;
#pragma unroll
    for (int s = 0; s < NS; ++s) {
        float4 w = *(const float4*)attnT[s];
#pragma unroll
        for (int c = 0; c < FCH; ++c) {
            float xv = xs[(size_t)s * FP + tid + c * 256];
            acc[0][c] += w.x * xv;
            acc[1][c] += w.y * xv;
            acc[2][c] += w.z * xv;
            acc[3][c] += w.w * xv;
        }
    }
#pragma unroll
    for (int c = 0; c < FCH; ++c)
#pragma unroll
        for (int h = 0; h < 4; ++h)
            xbar[h * F + tid + c * 256] = acc[h][c];
}

template <typename T, int F>
__device__ __forceinline__ void transform_o(const float* xbar, const T* w,
                                            float* dst, int tid) {
#pragma unroll
    for (int r = 0; r < 2; ++r) {
        int o = tid + r * 256;
        int h = o >> 7, d = o & 127;
        const T* wp = w + (size_t)h * F * 128 + d;
        const float* xb = xbar + (size_t)h * F;
        float a0 = 0.f, a1 = 0.f, a2 = 0.f, a3 = 0.f;
        for (int f = 0; f < F; f += 4) {
            a0 += xb[f + 0] * tof(wp[(size_t)(f + 0) * 128]);
            a1 += xb[f + 1] * tof(wp[(size_t)(f + 1) * 128]);
            a2 += xb[f + 2] * tof(wp[(size_t)(f + 2) * 128]);
            a3 += xb[f + 3] * tof(wp[(size_t)(f + 3) * 128]);
        }
        dst[o] = (a0 + a1) + (a2 + a3);
    }
}

template <typename T>
__device__ __forceinline__ void gat_body_fb(
    const T* x0, const T* x1, const T* x2, const T* w0, const T* a0s,
    const T* a0n, const T* w1, const T* a1s, const T* a1n, const T* fcw,
    T* out, float* xs, float* hs, float* xbar, float (*attnT)[4],
    float* part, float* hroot, int b, int tid)
{
    for (int p = 0; p < 10; ++p) {
        stage<T, 256, 26, 260>(xs, x1 + ((size_t)b * 10 + p) * 256,
                               x2 + ((size_t)b * 250 + (size_t)p * 25) * 256, tid);
        __syncthreads();
        attention2<T, 256, 26, 260>(xs, a0s, a0n, attnT, part, tid);
        aggregate2<256, 26, 260>(xs, attnT, xbar, tid);
        __syncthreads();
        transform_o<T, 256>(xbar, w0, &hs[(p + 1) * 516], tid);
        __syncthreads();
    }
    stage<T, 256, 11, 260>(xs, x0 + (size_t)b * 256, x1 + (size_t)b * 2560, tid);
    __syncthreads();
    attention2<T, 256, 11, 260>(xs, a0s, a0n, attnT, part, tid);
    aggregate2<256, 11, 260>(xs, attnT, xbar, tid);
    __syncthreads();
    transform_o<T, 256>(xbar, w0, &hs[0], tid);
    __syncthreads();
    attention2<T, 512, 11, 516>(hs, a1s, a1n, attnT, part, tid);
    aggregate2<512, 11, 516>(hs, attnT, xbar, tid);
    __syncthreads();
    transform_o<T, 512>(xbar, w1, hroot, tid);
    __syncthreads();
    const T* fp = fcw + tid;
    float a0 = 0.f, a1 = 0.f, a2 = 0.f, a3 = 0.f;
    for (int f = 0; f < 512; f += 4) {
        a0 += hroot[f + 0] * tof(fp[(size_t)(f + 0) * 256]);
        a1 += hroot[f + 1] * tof(fp[(size_t)(f + 1) * 256]);
        a2 += hroot[f + 2] * tof(fp[(size_t)(f + 2) * 256]);
        a3 += hroot[f + 3] * tof(fp[(size_t)(f + 3) * 256]);
    }
    store_val(&out[(size_t)b * 256 + tid], (a0 + a1) + (a2 + a3));
}

__global__ __launch_bounds__(256) void gat_fused(
    const void* x0, const void* x1, const void* x2, const void* w0,
    const void* a0s, const void* a0n, const void* w1, const void* a1s,
    const void* a1n, const void* fcw, void* out)
{
    const int b = blockIdx.x;
    const int tid = threadIdx.x;
    __shared__ __align__(16) float xs[26 * 260];
    __shared__ __align__(16) float hs[11 * 516];
    __shared__ __align__(16) float xbar[4 * 512];
    __shared__ __align__(16) float attnT[26][4];
    __shared__ float part[256];
    __shared__ __align__(16) float hroot[512];
    __shared__ int flag4[4];
    if (detect_ballot(x0, tid, flag4))
        gat_body_fb<float>((const float*)x0, (const float*)x1, (const float*)x2,
                           (const float*)w0, (const float*)a0s, (const float*)a0n,
                           (const float*)w1, (const float*)a1s, (const float*)a1n,
                           (const float*)fcw, (float*)out,
                           xs, hs, xbar, attnT, part, hroot, b, tid);
    else
        gat_body_fb<bf16>((const bf16*)x0, (const bf16*)x1, (const bf16*)x2,
                          (const bf16*)w0, (const bf16*)a0s, (const bf16*)a0n,
                          (const bf16*)w1, (const bf16*)a1s, (const bf16*)a1n,
                          (const bf16*)fcw, (bf16*)out,
                          xs, hs, xbar, attnT, part, hroot, b, tid);
}

extern "C" void kernel_launch(void* const* d_in, const int* in_sizes, int n_in,
                              void* d_out, int out_size, void* d_ws, size_t ws_size,
                              hipStream_t stream) {
    const int B = in_sizes[0] / 256;  // 1024
    // ws layout (floats): xbar0[B*11*1024] | hsws[B*11*512]  (~69.2 MB @ B=1024)
    const size_t ws_need = (size_t)B * 11 * 1536 * sizeof(float);

    if (d_ws && ws_size >= ws_need && ((B * 11) % 64) == 0 && (B % 4) == 0) {
        float* xbar0 = (float*)d_ws;
        float* hsws  = xbar0 + (size_t)B * 11 * 1024;
        gat_agg0v6<<<B * 11, 256, 0, stream>>>(d_in[0], d_in[1], d_in[2],
                                               d_in[4], d_in[5], xbar0);
        gat_gemm0<<<(B * 11 / 64) * 4, 256, 0, stream>>>(d_in[0], xbar0,
                                                         d_in[3], hsws);
        gat_root3<<<B / 4, 256, 0, stream>>>(d_in[0], hsws, d_in[6], d_in[7],
                                             d_in[8], d_in[9], d_out);
    } else {
        gat_fused<<<B, 256, 0, stream>>>(d_in[0], d_in[1], d_in[2], d_in[3],
                                         d_in[4], d_in[5], d_in[6], d_in[7],
                                         d_in[8], d_in[9], d_out);
    }
}